// Round 4
// baseline (2100.026 us; speedup 1.0000x reference)
//
#include <hip/hip_runtime.h>
#include <cfloat>
#include <climits>

#define T_TOKENS 65536
#define K_EMB 4096
#define D_DIM 256
#define QOFF ((size_t)T_TOKENS * D_DIM)   // 16777216
#define BT 128        // tokens per block
#define KTILE 256     // codes per k-tile (acc[8][16] per thread)
#define KHALF 2048    // codes per k-split half
#define NTILE (KHALF / KTILE)             // 8 k-tiles per half
#define DCH 16        // d-chunk width in floats (64 B rows)
#define NCHUNK (NTILE * (D_DIM / DCH))    // 128 chunks

// fp32 multiply, contraction into later add blocked (numpy rounds the square first)
__device__ __forceinline__ float fmul_nc(float a, float b) {
    float c = a * b;
    asm volatile("" : "+v"(c));
    return c;
}

__device__ __forceinline__ double wave_sum_d(double v) {
#pragma unroll
    for (int o = 32; o >= 1; o >>= 1) v += __shfl_down(v, o, 64);
    return v;
}

// async global->LDS DMA, 16B per lane; lds base must be wave-uniform.
__device__ __forceinline__ void glds16(const float* g, float* l) {
    __builtin_amdgcn_global_load_lds((const __attribute__((address_space(1))) void*)g,
                                     (__attribute__((address_space(3))) void*)l, 16, 0, 0);
}

// A32[t] = np.float32 pairwise sum of z[t]**2 (two 128-halves, 8 strided
// accumulators, ((r0+r1)+(r2+r3))+((r4+r5)+(r6+r7)), then h0+h1). Validated r4.
__global__ __launch_bounds__(256)
void a32_kernel(const float* __restrict__ z, float* __restrict__ a32) {
    __shared__ float lds[64][257];
    const int tid = threadIdx.x;
    const int t0 = blockIdx.x * 256;
    for (int sub = 0; sub < 4; sub++) {
        const int tb = t0 + sub * 64;
        __syncthreads();
        for (int idx = tid; idx < 64 * 256; idx += 256) {
            const int r = idx >> 8, c = idx & 255;
            lds[r][c] = z[(size_t)(tb + r) * D_DIM + c];
        }
        __syncthreads();
        if (tid < 64) {
            const float* row = lds[tid];
            float S[2];
            for (int h = 0; h < 2; h++) {
                const float* p = row + h * 128;
                float r[8];
#pragma unroll
                for (int j = 0; j < 8; j++) r[j] = fmul_nc(p[j], p[j]);
                for (int m = 1; m < 16; m++) {
#pragma unroll
                    for (int j = 0; j < 8; j++) r[j] += fmul_nc(p[8 * m + j], p[8 * m + j]);
                }
                S[h] = ((r[0] + r[1]) + (r[2] + r[3])) + ((r[4] + r[5]) + (r[6] + r[7]));
            }
            a32[tb + tid] = S[0] + S[1];
        }
    }
}

// C32[k] = fp32(||e_k||^2) — the +C add is annihilated by fp32 rounding anyway.
__global__ void c32_kernel(const float* __restrict__ emb, float* __restrict__ c32) {
    const int k = blockIdx.x;
    const double v = (double)emb[(size_t)k * D_DIM + threadIdx.x];
    double s = wave_sum_d(v * v);
    __shared__ double wsm[4];
    const int lane = threadIdx.x & 63, w = threadIdx.x >> 6;
    if (lane == 0) wsm[w] = s;
    __syncthreads();
    if (threadIdx.x == 0) c32[k] = (float)(wsm[0] + wsm[1] + wsm[2] + wsm[3]);
}

// Argmin GEMM, v4 (retry after infra failure): identical structure to v3
// (8x16 acc tile, DCH=16, dbuf LDS 48 KB, both-sides XOR swizzle), register
// allocation pinned to 2 waves/EU via amdgpu_waves_per_eu(2,2). v3 counters
// showed the compiler clamped arch VGPRs at 128 and shuffled ~half the
// accumulator pool through AGPRs (non-fma VALU cycles == fma cycles);
// 2 waves/EU budgets 256 arch VGPRs so acc/av/bw all live in arch registers.
// LDS (48KB -> 2 blocks/CU) already capped occupancy at this level.
__global__ __launch_bounds__(256)
__attribute__((amdgpu_waves_per_eu(2, 2)))
void argmin_np_kernel(const float* __restrict__ z, const float* __restrict__ emb,
                      const float* __restrict__ a32, const float* __restrict__ c32,
                      float* __restrict__ bvo, int* __restrict__ bio)
{
    __shared__ union {
        struct { float zt[2][BT * DCH]; float et[2][KTILE * DCH]; } t;   // 49152 B
        struct { float rb[16][BT]; int ri[16][BT]; } m;                  // 16384 B
    } sm;

    const int tid = threadIdx.x;
    const int tx = tid & 15;        // code group: codes 16j+tx, j=0..15
    const int ty = tid >> 4;        // token group: tokens 16i+ty, i=0..7
    const int t0 = blockIdx.x * BT;
    const int k0 = blockIdx.y * KHALF;

    // staging geometry: per glds16 a wave covers 16 rows x 64 B.
    const int wv = tid >> 6;               // wave id (0..3)
    const int lrow = (tid >> 2) & 15;      // lane row within 16-row stripe
    const int lslot = tid & 3;             // lane float4 position within row
    const int scol = ((lslot ^ ((lrow >> 1) & 3)) << 2);   // pre-swizzled src col (floats)
    const float* zsrc = z + (size_t)(t0 + wv * 32 + lrow) * D_DIM + scol;
    const float* esrc = emb + (size_t)(wv * 64 + lrow) * D_DIM + scol;
    const int zofs = (wv * 32) * DCH;      // wave-uniform float offsets in LDS tiles
    const int eofs = (wv * 64) * DCH;

    float a32r[8];
#pragma unroll
    for (int i = 0; i < 8; i++) a32r[i] = a32[t0 + 16 * i + ty];

    float bv[8];
    int bi[8];
#pragma unroll
    for (int i = 0; i < 8; i++) { bv[i] = FLT_MAX; bi[i] = INT_MAX; }

    float acc[8][16];
#pragma unroll
    for (int i = 0; i < 8; i++)
#pragma unroll
        for (int j = 0; j < 16; j++) acc[i][j] = 0.0f;

    // prologue: stage chunk 0 (k-tile 0, d-chunk 0) into buffer 0
#pragma unroll
    for (int s = 0; s < 2; s++)
        glds16(zsrc + (s << 12), &sm.t.zt[0][zofs + (s << 8)]);
#pragma unroll
    for (int s = 0; s < 4; s++)
        glds16(esrc + (size_t)k0 * D_DIM + (s << 12), &sm.t.et[0][eofs + (s << 8)]);
    __syncthreads();   // barrier drains vmcnt: buffer 0 ready

    const int tysw = (ty >> 1) & 3;   // read-side swizzle keys
    const int txsw = (tx >> 1) & 3;
    int p = 0;

    for (int ci = 0; ci < NCHUNK; ci++) {
        if (ci + 1 < NCHUNK) {   // DMA next chunk into the other buffer
            const int cn = ci + 1;
            const int dc = (cn & 15) << 4;                       // d offset (floats)
            const size_t ko = (size_t)(k0 + ((cn >> 4) << 8)) * D_DIM + dc;
            float* ztn = sm.t.zt[p ^ 1];
            float* etn = sm.t.et[p ^ 1];
#pragma unroll
            for (int s = 0; s < 2; s++)
                glds16(zsrc + dc + (s << 12), ztn + zofs + (s << 8));
#pragma unroll
            for (int s = 0; s < 4; s++)
                glds16(esrc + ko + (s << 12), etn + eofs + (s << 8));
        }
        // compute this chunk: d ascends (q*4 + {x,y,z,w}); chunks ascend in d
        // within a k-tile -> exact sequential 0..255 chain per acc.
        const float* zt0 = sm.t.zt[p];
        const float* et0 = sm.t.et[p];
        for (int q = 0; q < 4; q++) {
            const float* zb = zt0 + ty * DCH + ((q ^ tysw) << 2);
            const float* eb = et0 + tx * DCH + ((q ^ txsw) << 2);
            float4 av[8];
#pragma unroll
            for (int i = 0; i < 8; i++) av[i] = *(const float4*)(zb + (i << 8));
#pragma unroll
            for (int jh = 0; jh < 2; jh++) {
                float4 bw[8];
#pragma unroll
                for (int jj = 0; jj < 8; jj++)
                    bw[jj] = *(const float4*)(eb + ((jh * 8 + jj) << 8));
#pragma unroll
                for (int i = 0; i < 8; i++)
#pragma unroll
                    for (int jj = 0; jj < 8; jj++) {
                        float* a = &acc[i][jh * 8 + jj];
                        *a = fmaf(av[i].x, bw[jj].x, *a);
                        *a = fmaf(av[i].y, bw[jj].y, *a);
                        *a = fmaf(av[i].z, bw[jj].z, *a);
                        *a = fmaf(av[i].w, bw[jj].w, *a);
                    }
            }
        }
        if ((ci & 15) == 15) {   // k-tile epilogue: V = fl32(fl32(A-2M)+C), argmin
            const int kb = k0 + ((ci >> 4) << 8);
#pragma unroll
            for (int j = 0; j < 16; j++) {
                const int k = kb + 16 * j + tx;   // per-thread k strictly ascending
                const float ck = c32[k];
#pragma unroll
                for (int i = 0; i < 8; i++) {
                    const float v1 = a32r[i] - 2.0f * acc[i][j];
                    const float v2 = v1 + ck;
                    if (v2 < bv[i]) { bv[i] = v2; bi[i] = k; }
                    acc[i][j] = 0.0f;
                }
            }
        }
        __syncthreads();   // readers of buf p done; DMA into p^1 drained
        p ^= 1;
    }

    // tiles dead; reuse LDS for merge
#pragma unroll
    for (int i = 0; i < 8; i++) {
        sm.m.rb[tx][16 * i + ty] = bv[i];
        sm.m.ri[tx][16 * i + ty] = bi[i];
    }
    __syncthreads();
    if (tid < BT) {
        float B = sm.m.rb[0][tid];
        int I = sm.m.ri[0][tid];
#pragma unroll
        for (int e = 1; e < 16; e++) {
            const float cv = sm.m.rb[e][tid];
            const int ci2 = sm.m.ri[e][tid];
            if (cv < B || (cv == B && ci2 < I)) { B = cv; I = ci2; }
        }
        bvo[(size_t)blockIdx.y * T_TOKENS + t0 + tid] = B;
        bio[(size_t)blockIdx.y * T_TOKENS + t0 + tid] = I;
    }
}

// Merge k-split halves, gather quantized rows, write indices, fp64 loss partials.
__global__ __launch_bounds__(256)
void gather_kernel(const float* __restrict__ z, const float* __restrict__ emb,
                   const float* __restrict__ bvh, const int* __restrict__ bih,
                   float* __restrict__ out, double* __restrict__ partials)
{
    const int tid = threadIdx.x;
    const int base = blockIdx.x * 64;
    __shared__ double lsm[4];
    double lacc = 0.0;
    for (int ti = 0; ti < 64; ti++) {
        const int t = base + ti;
        // numpy first-index: tie -> half 0 (its ks are all smaller)
        const int sel = (bvh[T_TOKENS + t] < bvh[t]) ? bih[T_TOKENS + t] : bih[t];
        const float ev = emb[(size_t)sel * D_DIM + tid];
        const float zv = z[(size_t)t * D_DIM + tid];
        out[(size_t)t * D_DIM + tid] = ev;
        if (tid == 0) out[QOFF + t] = (float)sel;
        const double df = (double)zv - (double)ev;
        lacc += df * df;
    }
    lacc = wave_sum_d(lacc);
    const int lane = tid & 63, w = tid >> 6;
    if (lane == 0) lsm[w] = lacc;
    __syncthreads();
    if (tid == 0) partials[blockIdx.x] = lsm[0] + lsm[1] + lsm[2] + lsm[3];
}

__global__ void finalize_kernel(const double* __restrict__ partials, float* __restrict__ out) {
    __shared__ double rsm[4];
    const int tid = threadIdx.x;
    double s = 0.0;
    for (int i = tid; i < 1024; i += 256) s += partials[i];
    s = wave_sum_d(s);
    if ((tid & 63) == 0) rsm[tid >> 6] = s;
    __syncthreads();
    if (tid == 0) {
        const double mean = (rsm[0] + rsm[1] + rsm[2] + rsm[3]) / (double)QOFF;
        out[QOFF + T_TOKENS] = (float)(1.25 * mean);
    }
}

extern "C" void kernel_launch(void* const* d_in, const int* in_sizes, int n_in,
                              void* d_out, int out_size, void* d_ws, size_t ws_size,
                              hipStream_t stream)
{
    const float* z = (const float*)d_in[0];
    const float* emb = (const float*)d_in[1];
    float* out = (float*)d_out;
    char* ws = (char*)d_ws;

    float* a32 = (float*)ws;                          // 262144 B
    float* c32 = (float*)(ws + 262144);               // 16384 B
    float* bvh = (float*)(ws + 278528);               // 2*65536*4 = 524288 B
    int* bih = (int*)(ws + 802816);                   // 524288 B
    double* partials = (double*)(ws + 1327104);       // 8192 B

    a32_kernel<<<T_TOKENS / 256, 256, 0, stream>>>(z, a32);
    c32_kernel<<<K_EMB, 256, 0, stream>>>(emb, c32);
    argmin_np_kernel<<<dim3(T_TOKENS / BT, 2), 256, 0, stream>>>(z, emb, a32, c32, bvh, bih);
    gather_kernel<<<T_TOKENS / 64, 256, 0, stream>>>(z, emb, bvh, bih, out, partials);
    finalize_kernel<<<1, 256, 0, stream>>>(partials, out);
}

// Round 5
// 871.286 us; speedup vs baseline: 2.4103x; 2.4103x over previous
//
#include <hip/hip_runtime.h>
#include <cfloat>
#include <climits>

#define T_TOKENS 65536
#define K_EMB 4096
#define D_DIM 256
#define QOFF ((size_t)T_TOKENS * D_DIM)   // 16777216

using bf16x8 = __attribute__((ext_vector_type(8))) short;
using f32x16 = __attribute__((ext_vector_type(16))) float;

// fp32 multiply, contraction into later add blocked (numpy rounds the square first)
__device__ __forceinline__ float fmul_nc(float a, float b) {
    float c = a * b;
    asm volatile("" : "+v"(c));
    return c;
}

__device__ __forceinline__ double wave_sum_d(double v) {
#pragma unroll
    for (int o = 32; o >= 1; o >>= 1) v += __shfl_down(v, o, 64);
    return v;
}

// async global->LDS DMA, 16B per lane; lds base must be wave-uniform.
__device__ __forceinline__ void glds16(const void* g, void* l) {
    __builtin_amdgcn_global_load_lds((const __attribute__((address_space(1))) void*)g,
                                     (__attribute__((address_space(3))) void*)l, 16, 0, 0);
}

// round-to-nearest-even fp32 -> bf16 bits
__device__ __forceinline__ unsigned short f2bf(float f) {
    unsigned u = __float_as_uint(f);
    u += 0x7FFFu + ((u >> 16) & 1u);
    return (unsigned short)(u >> 16);
}
__device__ __forceinline__ float bf2f(unsigned short h) {
    return __uint_as_float((unsigned)h << 16);
}

// A32[t] = np.float32 pairwise sum of z[t]**2 (two 128-halves, 8 strided
// accumulators, ((r0+r1)+(r2+r3))+((r4+r5)+(r6+r7)), then h0+h1). Validated r4.
__global__ __launch_bounds__(256)
void a32_kernel(const float* __restrict__ z, float* __restrict__ a32) {
    __shared__ float lds[64][257];
    const int tid = threadIdx.x;
    const int t0 = blockIdx.x * 256;
    for (int sub = 0; sub < 4; sub++) {
        const int tb = t0 + sub * 64;
        __syncthreads();
        for (int idx = tid; idx < 64 * 256; idx += 256) {
            const int r = idx >> 8, c = idx & 255;
            lds[r][c] = z[(size_t)(tb + r) * D_DIM + c];
        }
        __syncthreads();
        if (tid < 64) {
            const float* row = lds[tid];
            float S[2];
            for (int h = 0; h < 2; h++) {
                const float* p = row + h * 128;
                float r[8];
#pragma unroll
                for (int j = 0; j < 8; j++) r[j] = fmul_nc(p[j], p[j]);
                for (int m = 1; m < 16; m++) {
#pragma unroll
                    for (int j = 0; j < 8; j++) r[j] += fmul_nc(p[8 * m + j], p[8 * m + j]);
                }
                S[h] = ((r[0] + r[1]) + (r[2] + r[3])) + ((r[4] + r[5]) + (r[6] + r[7]));
            }
            a32[tb + tid] = S[0] + S[1];
        }
    }
}

// C32[k] = fp32(||e_k||^2)
__global__ void c32_kernel(const float* __restrict__ emb, float* __restrict__ c32) {
    const int k = blockIdx.x;
    const double v = (double)emb[(size_t)k * D_DIM + threadIdx.x];
    double s = wave_sum_d(v * v);
    __shared__ double wsm[4];
    const int lane = threadIdx.x & 63, w = threadIdx.x >> 6;
    if (lane == 0) wsm[w] = s;
    __syncthreads();
    if (threadIdx.x == 0) c32[k] = (float)(wsm[0] + wsm[1] + wsm[2] + wsm[3]);
}

// Split emb fp32 -> bf16 hi + bf16 lo(residual), RNE.
__global__ __launch_bounds__(256)
void split_emb_kernel(const float* __restrict__ emb, unsigned short* __restrict__ ehi,
                      unsigned short* __restrict__ elo) {
    const size_t i4 = (size_t)blockIdx.x * 256 + threadIdx.x;   // 262144 float4s
    const float4 v = *(const float4*)(emb + i4 * 4);
    ushort4 h, l;
    h.x = f2bf(v.x); l.x = f2bf(v.x - bf2f(h.x));
    h.y = f2bf(v.y); l.y = f2bf(v.y - bf2f(h.y));
    h.z = f2bf(v.z); l.z = f2bf(v.z - bf2f(h.z));
    h.w = f2bf(v.w); l.w = f2bf(v.w - bf2f(h.w));
    *(ushort4*)(ehi + i4 * 4) = h;
    *(ushort4*)(elo + i4 * 4) = l;
}

// MFMA candidate filter. Per block: 128 tokens (4 waves x 32 cols), all 4096
// codes in 128 tiles of 32. A = emb tile (rows=codes) from LDS (bf16 hi/lo,
// XOR-swizzled: slot s of row r holds global chunk s^(r&7) -> conflict-free
// ds_read_b128); B = z frags in registers (bf16 hi/lo split in-kernel).
// Maximizing acc ~ z.e with 3 mfma/step into 3 accs (dep-chain break):
// M~ = zh.eh + zh.el + zl.eh  (lo.lo term <= 1e-7, irrelevant at thr).
// Per lane best-6 (its 16-of-32 code rows per tile); 12 cand/token out.
// Exact argmin recovered later by rescoring candidates with the validated
// fp32 chain; window 8e-5 in acc units covers the hard error bound 4.8e-5/2.
__global__ __launch_bounds__(256)
void argmin_mfma_kernel(const float* __restrict__ z,
                        const unsigned short* __restrict__ ehi,
                        const unsigned short* __restrict__ elo,
                        float* __restrict__ cacc, int* __restrict__ cidx)
{
    __shared__ short lds_e[2][2][32 * 256];   // [buf][hi/lo][row*256+col] 64 KiB

    const int tid = threadIdx.x;
    const int wv  = tid >> 6;
    const int l   = tid & 63;
    const int lr  = l & 31;          // A-row (code) and D-col (token) lane index
    const int h   = l >> 5;          // k-half
    const int tok = blockIdx.x * 128 + wv * 32 + lr;

    // ---- load this lane's z fragments (fp32), split to bf16 hi/lo ----
    bf16x8 zh[16], zl[16];
#pragma unroll
    for (int st = 0; st < 16; st++) {
        const float* zp = z + (size_t)tok * D_DIM + st * 16 + h * 8;
        const float4 f0 = *(const float4*)zp;
        const float4 f1 = *(const float4*)(zp + 4);
        const float f[8] = {f0.x, f0.y, f0.z, f0.w, f1.x, f1.y, f1.z, f1.w};
#pragma unroll
        for (int j = 0; j < 8; j++) {
            const unsigned short hb = f2bf(f[j]);
            zh[st][j] = (short)hb;
            zl[st][j] = (short)f2bf(f[j] - bf2f(hb));
        }
    }

    float bb[6]; int bk[6];
#pragma unroll
    for (int s = 0; s < 6; s++) { bb[s] = -FLT_MAX; bk[s] = INT_MAX; }

    // stage tile ct into buf: 32 glds16 (1KB each), 8 per wave; source column
    // pre-swizzled so linear LDS dest + swizzled read = involution.
    auto stage = [&](int buf, int ct) {
#pragma unroll
        for (int q = 0; q < 8; q++) {
            const int idx = wv * 8 + q;
            const int hsel = idx >> 4;          // 0: hi, 1: lo
            const int rp = idx & 15;            // row pair
            const int r = 2 * rp + (l >> 5);
            const int g = (l & 31) ^ (r & 7);   // pre-swizzled source chunk
            const unsigned short* src =
                (hsel ? elo : ehi) + (size_t)(ct * 32 + r) * D_DIM + g * 8;
            glds16(src, &lds_e[buf][hsel][(2 * rp) * 256]);
        }
    };

    stage(0, 0);
    __syncthreads();

    int buf = 0;
    for (int ct = 0; ct < 128; ct++) {
        if (ct + 1 < 128) stage(buf ^ 1, ct + 1);

        f32x16 aP, aQ, aR;
#pragma unroll
        for (int i = 0; i < 16; i++) { aP[i] = 0.0f; aQ[i] = 0.0f; aR[i] = 0.0f; }

        const short* ehb = &lds_e[buf][0][0];
        const short* elb = &lds_e[buf][1][0];
#pragma unroll
        for (int st = 0; st < 16; st++) {
            const int slot = ((2 * st + h) ^ (lr & 7)) * 8;
            const bf16x8 eh = *(const bf16x8*)(ehb + lr * 256 + slot);
            const bf16x8 el = *(const bf16x8*)(elb + lr * 256 + slot);
            aP = __builtin_amdgcn_mfma_f32_32x32x16_bf16(eh, zh[st], aP, 0, 0, 0);
            aQ = __builtin_amdgcn_mfma_f32_32x32x16_bf16(el, zh[st], aQ, 0, 0, 0);
            aR = __builtin_amdgcn_mfma_f32_32x32x16_bf16(eh, zl[st], aR, 0, 0, 0);
        }

        // epilogue: best-6 insert (VALU pipe, hides under MFMA)
#pragma unroll
        for (int r = 0; r < 16; r++) {
            float cv = (aP[r] + aQ[r]) + aR[r];
            int ck = ct * 32 + (r & 3) + 8 * (r >> 2) + 4 * h;
#pragma unroll
            for (int s = 0; s < 6; s++) {
                const bool gt = cv > bb[s];
                const float tv = bb[s]; const int tk = bk[s];
                bb[s] = gt ? cv : bb[s]; bk[s] = gt ? ck : bk[s];
                cv = gt ? tv : cv;       ck = gt ? tk : ck;
            }
        }
        __syncthreads();   // next tile staged; this buf's readers done
        buf ^= 1;
    }

#pragma unroll
    for (int s = 0; s < 6; s++) {
        cacc[(size_t)tok * 12 + h * 6 + s] = bb[s];
        cidx[(size_t)tok * 12 + h * 6 + s] = bk[s];
    }
}

// Rescore candidates with the bit-exact validated fp32 chain, select winner
// (first-min: strictly-less, tie -> smaller k), gather rows, fp64 loss.
__global__ __launch_bounds__(256)
void rescore_gather_kernel(const float* __restrict__ z, const float* __restrict__ emb,
                           const float* __restrict__ a32, const float* __restrict__ c32,
                           const float* __restrict__ cacc, const int* __restrict__ cidx,
                           float* __restrict__ out, double* __restrict__ partials)
{
    __shared__ float zt[64][257];
    __shared__ int win[64];
    __shared__ double lsm[4];
    const int tid = threadIdx.x;
    const int base = blockIdx.x * 64;

    for (int idx = tid; idx < 64 * 256; idx += 256) {
        const int r = idx >> 8, c = idx & 255;
        zt[r][c] = z[(size_t)(base + r) * D_DIM + c];
    }
    __syncthreads();

    if (tid < 64) {
        const int t = base + tid;
        float amax = -FLT_MAX;
        for (int s = 0; s < 12; s++) amax = fmaxf(amax, cacc[(size_t)t * 12 + s]);
        const float thr = amax - 8e-5f;
        const float ar = a32[t];
        float bestv = FLT_MAX; int bestk = INT_MAX;
        for (int s = 0; s < 12; s++) {
            if (cacc[(size_t)t * 12 + s] >= thr) {
                const int k = cidx[(size_t)t * 12 + s];
                const float* er = emb + (size_t)k * D_DIM;
                float m = 0.0f;
#pragma unroll 8
                for (int d4 = 0; d4 < 64; d4++) {
                    const float4 e4 = *(const float4*)(er + 4 * d4);
                    m = fmaf(zt[tid][4 * d4 + 0], e4.x, m);
                    m = fmaf(zt[tid][4 * d4 + 1], e4.y, m);
                    m = fmaf(zt[tid][4 * d4 + 2], e4.z, m);
                    m = fmaf(zt[tid][4 * d4 + 3], e4.w, m);
                }
                const float v1 = ar - 2.0f * m;
                const float v2 = v1 + c32[k];
                if (v2 < bestv || (v2 == bestv && k < bestk)) { bestv = v2; bestk = k; }
            }
        }
        win[tid] = bestk;
    }
    __syncthreads();

    double lacc = 0.0;
    for (int ti = 0; ti < 64; ti++) {
        const int sel = win[ti];
        const float ev = emb[(size_t)sel * D_DIM + tid];
        const float zv = zt[ti][tid];
        out[(size_t)(base + ti) * D_DIM + tid] = ev;
        if (tid == 0) out[QOFF + base + ti] = (float)sel;
        const double df = (double)zv - (double)ev;
        lacc += df * df;
    }
    lacc = wave_sum_d(lacc);
    const int lane = tid & 63, w = tid >> 6;
    if (lane == 0) lsm[w] = lacc;
    __syncthreads();
    if (tid == 0) partials[blockIdx.x] = lsm[0] + lsm[1] + lsm[2] + lsm[3];
}

__global__ void finalize_kernel(const double* __restrict__ partials, float* __restrict__ out) {
    __shared__ double rsm[4];
    const int tid = threadIdx.x;
    double s = 0.0;
    for (int i = tid; i < 1024; i += 256) s += partials[i];
    s = wave_sum_d(s);
    if ((tid & 63) == 0) rsm[tid >> 6] = s;
    __syncthreads();
    if (tid == 0) {
        const double mean = (rsm[0] + rsm[1] + rsm[2] + rsm[3]) / (double)QOFF;
        out[QOFF + T_TOKENS] = (float)(1.25 * mean);
    }
}

extern "C" void kernel_launch(void* const* d_in, const int* in_sizes, int n_in,
                              void* d_out, int out_size, void* d_ws, size_t ws_size,
                              hipStream_t stream)
{
    const float* z = (const float*)d_in[0];
    const float* emb = (const float*)d_in[1];
    float* out = (float*)d_out;
    char* ws = (char*)d_ws;

    float* a32 = (float*)ws;                              // 262144 B
    float* c32 = (float*)(ws + 262144);                   // 16384 B
    float* cacc = (float*)(ws + 278528);                  // 65536*12*4 = 3145728 B
    int* cidx = (int*)(ws + 3424256);                     // 3145728 B
    unsigned short* ehi = (unsigned short*)(ws + 6569984);   // 2097152 B
    unsigned short* elo = (unsigned short*)(ws + 8667136);   // 2097152 B
    double* partials = (double*)(ws + 10764288);          // 8192 B

    split_emb_kernel<<<1024, 256, 0, stream>>>(emb, ehi, elo);
    a32_kernel<<<T_TOKENS / 256, 256, 0, stream>>>(z, a32);
    c32_kernel<<<K_EMB, 256, 0, stream>>>(emb, c32);
    argmin_mfma_kernel<<<T_TOKENS / 128, 256, 0, stream>>>(z, ehi, elo, cacc, cidx);
    rescore_gather_kernel<<<T_TOKENS / 64, 256, 0, stream>>>(z, emb, a32, c32, cacc, cidx, out, partials);
    finalize_kernel<<<1, 256, 0, stream>>>(partials, out);
}

// Round 6
// 462.030 us; speedup vs baseline: 4.5452x; 1.8858x over previous
//
#include <hip/hip_runtime.h>
#include <cfloat>
#include <climits>

#define T_TOKENS 65536
#define K_EMB 4096
#define D_DIM 256
#define QOFF ((size_t)T_TOKENS * D_DIM)   // 16777216
#define WINDOW 1.2e-4f                     // rescue window in biased-score units
#define B0 0.03125f                        // positivity bias baked into acc init

using bf16x8 = __attribute__((ext_vector_type(8))) short;
using f32x16 = __attribute__((ext_vector_type(16))) float;

// fp32 multiply, contraction into later add blocked (numpy rounds the square first)
__device__ __forceinline__ float fmul_nc(float a, float b) {
    float c = a * b;
    asm volatile("" : "+v"(c));
    return c;
}

__device__ __forceinline__ double wave_sum_d(double v) {
#pragma unroll
    for (int o = 32; o >= 1; o >>= 1) v += __shfl_down(v, o, 64);
    return v;
}

// async global->LDS DMA, 16B per lane; lds base must be wave-uniform.
__device__ __forceinline__ void glds16(const void* g, void* l) {
    __builtin_amdgcn_global_load_lds((const __attribute__((address_space(1))) void*)g,
                                     (__attribute__((address_space(3))) void*)l, 16, 0, 0);
}

// round-to-nearest-even fp32 -> bf16 bits
__device__ __forceinline__ unsigned short f2bf(float f) {
    unsigned u = __float_as_uint(f);
    u += 0x7FFFu + ((u >> 16) & 1u);
    return (unsigned short)(u >> 16);
}

// A32[t] = np.float32 pairwise sum of z[t]**2 (validated round-4 chain).
__global__ __launch_bounds__(256)
void a32_kernel(const float* __restrict__ z, float* __restrict__ a32) {
    __shared__ float lds[64][257];
    const int tid = threadIdx.x;
    const int t0 = blockIdx.x * 256;
    for (int sub = 0; sub < 4; sub++) {
        const int tb = t0 + sub * 64;
        __syncthreads();
        for (int idx = tid; idx < 64 * 256; idx += 256) {
            const int r = idx >> 8, c = idx & 255;
            lds[r][c] = z[(size_t)(tb + r) * D_DIM + c];
        }
        __syncthreads();
        if (tid < 64) {
            const float* row = lds[tid];
            float S[2];
            for (int h = 0; h < 2; h++) {
                const float* p = row + h * 128;
                float r[8];
#pragma unroll
                for (int j = 0; j < 8; j++) r[j] = fmul_nc(p[j], p[j]);
                for (int m = 1; m < 16; m++) {
#pragma unroll
                    for (int j = 0; j < 8; j++) r[j] += fmul_nc(p[8 * m + j], p[8 * m + j]);
                }
                S[h] = ((r[0] + r[1]) + (r[2] + r[3])) + ((r[4] + r[5]) + (r[6] + r[7]));
            }
            a32[tb + tid] = S[0] + S[1];
        }
    }
}

// C32[k] = fp32(||e_k||^2)
__global__ void c32_kernel(const float* __restrict__ emb, float* __restrict__ c32) {
    const int k = blockIdx.x;
    const double v = (double)emb[(size_t)k * D_DIM + threadIdx.x];
    double s = wave_sum_d(v * v);
    __shared__ double wsm[4];
    const int lane = threadIdx.x & 63, w = threadIdx.x >> 6;
    if (lane == 0) wsm[w] = s;
    __syncthreads();
    if (threadIdx.x == 0) c32[k] = (float)(wsm[0] + wsm[1] + wsm[2] + wsm[3]);
}

// emb fp32 -> bf16 hi (RNE). Lo residual no longer needed (single-mfma filter).
__global__ __launch_bounds__(256)
void split_hi_kernel(const float* __restrict__ emb, unsigned short* __restrict__ ehi) {
    const size_t i4 = (size_t)blockIdx.x * 256 + threadIdx.x;   // 262144 float4s
    const float4 v = *(const float4*)(emb + i4 * 4);
    ushort4 hh;
    hh.x = f2bf(v.x); hh.y = f2bf(v.y); hh.z = f2bf(v.z); hh.w = f2bf(v.w);
    *(ushort4*)(ehi + i4 * 4) = hh;
}

// MFMA candidate filter v6: single mfma (zh.eh), e-hi LDS dbuf 32 KB, k-split x2
// (blockIdx.y half of 2048 codes, 64 tiles of 32), 4 blocks/CU via
// __launch_bounds__(256,4). Scores biased by B0 (via acc init) -> positive ->
// float bits monotone as u32 -> pack global code id in low 12 bits -> top-4
// per lane-half is a pure v_max/min_u32 chain. Exact argmin recovered by
// rescoring keys within WINDOW with the validated fp32 chain.
__global__ __launch_bounds__(256, 4)
void argmin_mfma_kernel(const float* __restrict__ z,
                        const unsigned short* __restrict__ ehi,
                        unsigned int* __restrict__ keyout)
{
    __shared__ short lds_e[2][32 * 256];   // 2 x 16 KiB

    const int tid = threadIdx.x;
    const int wv  = tid >> 6;
    const int l   = tid & 63;
    const int lr  = l & 31;          // A-row (code) / D-col (token) lane index
    const int h   = l >> 5;          // k-half within the mfma fragment
    const int tok = blockIdx.x * 128 + wv * 32 + lr;
    const int kbase = blockIdx.y * 2048;

    // z fragments, bf16 hi only (64 VGPR)
    bf16x8 zh[16];
#pragma unroll
    for (int st = 0; st < 16; st++) {
        const float* zp = z + (size_t)tok * D_DIM + st * 16 + h * 8;
        const float4 f0 = *(const float4*)zp;
        const float4 f1 = *(const float4*)(zp + 4);
        const float f[8] = {f0.x, f0.y, f0.z, f0.w, f1.x, f1.y, f1.z, f1.w};
#pragma unroll
        for (int j = 0; j < 8; j++) zh[st][j] = (short)f2bf(f[j]);
    }

    unsigned b1 = 0u, b2 = 0u, b3 = 0u, b4 = 0u;

    // stage tile ct: 16 glds16 (4/wave), 2 rows per request; source chunk
    // pre-swizzled g = (l&31)^(r&7) so linear LDS dest + swizzled read match.
    // r&7 = 2q | h  (since (wv*4+q)&3 == q).
    auto stage = [&](int buf, int ct) {
#pragma unroll
        for (int q = 0; q < 4; q++) {
            const int rp = wv * 4 + q;
            const int r  = 2 * rp + h;
            const int g  = lr ^ ((2 * q) | h);
            const unsigned short* src =
                ehi + (size_t)(kbase + ct * 32 + r) * D_DIM + g * 8;
            glds16(src, &lds_e[buf][rp * 512]);
        }
    };

    stage(0, 0);
    __syncthreads();

    const int lk = lr & 7;
    const short* lrow0 = &lds_e[0][lr * 256];
    const short* lrow1 = &lds_e[1][lr * 256];
    const unsigned vh4 = (unsigned)(4 * h);

    int buf = 0;
    for (int ct = 0; ct < 64; ct++) {
        if (ct + 1 < 64) stage(buf ^ 1, ct + 1);

        f32x16 aP;
#pragma unroll
        for (int i = 0; i < 16; i++) aP[i] = B0;   // bias injected free

        const short* lrow = buf ? lrow1 : lrow0;
#pragma unroll
        for (int st = 0; st < 16; st++) {
            const bf16x8 eh = *(const bf16x8*)(lrow + (((2 * st + h) ^ lk) << 3));
            aP = __builtin_amdgcn_mfma_f32_32x32x16_bf16(eh, zh[st], aP, 0, 0, 0);
        }

        // epilogue: pack biased score + code id, keep top-4 (max/min chain)
        const unsigned korb = (unsigned)(kbase + ct * 32) | vh4;
#pragma unroll
        for (int r = 0; r < 16; r++) {
            const float cv = fmaxf(aP[r], 1e-6f);   // positivity insurance
            unsigned t = (__float_as_uint(cv) & 0xFFFFF000u) | korb
                         | (unsigned)((r & 3) + 8 * (r >> 2));
            const unsigned n1 = b1 > t ? b1 : t; t = b1 > t ? t : b1; b1 = n1;
            const unsigned n2 = b2 > t ? b2 : t; t = b2 > t ? t : b2; b2 = n2;
            const unsigned n3 = b3 > t ? b3 : t; t = b3 > t ? t : b3; b3 = n3;
            b4 = b4 > t ? b4 : t;
        }
        __syncthreads();   // readers of buf done; DMA into buf^1 drained
        buf ^= 1;
    }

    // coalesced: per token 8 dwords (h=0 then h=1), k-halves stacked by T.
    *(uint4*)(keyout + (((size_t)blockIdx.y * T_TOKENS + tok) << 3) + vh4) =
        make_uint4(b1, b2, b3, b4);
}

// Merge 16 keys/token, rescore window candidates with the bit-exact validated
// fp32 chain, select (strict-less, tie -> smaller k), gather rows, fp64 loss.
__global__ __launch_bounds__(256)
void rescore_gather_kernel(const float* __restrict__ z, const float* __restrict__ emb,
                           const float* __restrict__ a32, const float* __restrict__ c32,
                           const unsigned int* __restrict__ keyout,
                           float* __restrict__ out, double* __restrict__ partials)
{
    __shared__ float zt[64][257];
    __shared__ int win[64];
    __shared__ double lsm[4];
    const int tid = threadIdx.x;
    const int base = blockIdx.x * 64;

    for (int idx = tid; idx < 64 * 256; idx += 256) {
        const int r = idx >> 8, c = idx & 255;
        zt[r][c] = z[(size_t)(base + r) * D_DIM + c];
    }
    __syncthreads();

    if (tid < 64) {
        const int t = base + tid;
        unsigned keys[16];
        const uint4 k0 = *(const uint4*)(keyout + ((size_t)t << 3));
        const uint4 k1 = *(const uint4*)(keyout + ((size_t)t << 3) + 4);
        const uint4 k2 = *(const uint4*)(keyout + ((size_t)(T_TOKENS + t) << 3));
        const uint4 k3 = *(const uint4*)(keyout + ((size_t)(T_TOKENS + t) << 3) + 4);
        keys[0] = k0.x; keys[1] = k0.y; keys[2] = k0.z; keys[3] = k0.w;
        keys[4] = k1.x; keys[5] = k1.y; keys[6] = k1.z; keys[7] = k1.w;
        keys[8] = k2.x; keys[9] = k2.y; keys[10] = k2.z; keys[11] = k2.w;
        keys[12] = k3.x; keys[13] = k3.y; keys[14] = k3.z; keys[15] = k3.w;
        float maxF = 0.0f;
#pragma unroll
        for (int s = 0; s < 16; s++) maxF = fmaxf(maxF, __uint_as_float(keys[s]));
        const float thr = maxF - WINDOW;
        const float ar = a32[t];
        float bestv = FLT_MAX; int bestk = INT_MAX;
        for (int s = 0; s < 16; s++) {
            if (__uint_as_float(keys[s]) >= thr) {
                const int k = (int)(keys[s] & 0xFFFu);
                const float* er = emb + (size_t)k * D_DIM;
                float m = 0.0f;
#pragma unroll 8
                for (int d4 = 0; d4 < 64; d4++) {
                    const float4 e4 = *(const float4*)(er + 4 * d4);
                    m = fmaf(zt[tid][4 * d4 + 0], e4.x, m);
                    m = fmaf(zt[tid][4 * d4 + 1], e4.y, m);
                    m = fmaf(zt[tid][4 * d4 + 2], e4.z, m);
                    m = fmaf(zt[tid][4 * d4 + 3], e4.w, m);
                }
                const float v1 = ar - 2.0f * m;
                const float v2 = v1 + c32[k];
                if (v2 < bestv || (v2 == bestv && k < bestk)) { bestv = v2; bestk = k; }
            }
        }
        win[tid] = bestk;
    }
    __syncthreads();

    double lacc = 0.0;
    for (int ti = 0; ti < 64; ti++) {
        const int sel = win[ti];
        const float ev = emb[(size_t)sel * D_DIM + tid];
        const float zv = zt[ti][tid];
        out[(size_t)(base + ti) * D_DIM + tid] = ev;
        if (tid == 0) out[QOFF + base + ti] = (float)sel;
        const double df = (double)zv - (double)ev;
        lacc += df * df;
    }
    lacc = wave_sum_d(lacc);
    const int lane = tid & 63, w = tid >> 6;
    if (lane == 0) lsm[w] = lacc;
    __syncthreads();
    if (tid == 0) partials[blockIdx.x] = lsm[0] + lsm[1] + lsm[2] + lsm[3];
}

__global__ void finalize_kernel(const double* __restrict__ partials, float* __restrict__ out) {
    __shared__ double rsm[4];
    const int tid = threadIdx.x;
    double s = 0.0;
    for (int i = tid; i < 1024; i += 256) s += partials[i];
    s = wave_sum_d(s);
    if ((tid & 63) == 0) rsm[tid >> 6] = s;
    __syncthreads();
    if (tid == 0) {
        const double mean = (rsm[0] + rsm[1] + rsm[2] + rsm[3]) / (double)QOFF;
        out[QOFF + T_TOKENS] = (float)(1.25 * mean);
    }
}

extern "C" void kernel_launch(void* const* d_in, const int* in_sizes, int n_in,
                              void* d_out, int out_size, void* d_ws, size_t ws_size,
                              hipStream_t stream)
{
    const float* z = (const float*)d_in[0];
    const float* emb = (const float*)d_in[1];
    float* out = (float*)d_out;
    char* ws = (char*)d_ws;

    float* a32 = (float*)ws;                                  // 262144 B
    float* c32 = (float*)(ws + 262144);                       // 16384 B
    unsigned int* keyout = (unsigned int*)(ws + 278528);      // 2*65536*8*4 = 4194304 B
    unsigned short* ehi = (unsigned short*)(ws + 4472832);    // 2097152 B
    double* partials = (double*)(ws + 6569984);               // 8192 B

    split_hi_kernel<<<1024, 256, 0, stream>>>(emb, ehi);
    a32_kernel<<<T_TOKENS / 256, 256, 0, stream>>>(z, a32);
    c32_kernel<<<K_EMB, 256, 0, stream>>>(emb, c32);
    argmin_mfma_kernel<<<dim3(T_TOKENS / 128, 2), 256, 0, stream>>>(z, ehi, keyout);
    rescore_gather_kernel<<<T_TOKENS / 64, 256, 0, stream>>>(z, emb, a32, c32, keyout, out, partials);
    finalize_kernel<<<1, 256, 0, stream>>>(partials, out);
}

// Round 7
// 372.431 us; speedup vs baseline: 5.6387x; 1.2406x over previous
//
#include <hip/hip_runtime.h>
#include <cfloat>
#include <climits>

#define T_TOKENS 65536
#define K_EMB 4096
#define D_DIM 256
#define QOFF ((size_t)T_TOKENS * D_DIM)   // 16777216
#define WINDOW 1.2e-4f                     // rescue window in biased-score units
#define B0 0.03125f                        // positivity bias baked into acc init

using bf16x8 = __attribute__((ext_vector_type(8))) short;
using f32x16 = __attribute__((ext_vector_type(16))) float;

// fp32 multiply, contraction into later add blocked (numpy rounds the square first)
__device__ __forceinline__ float fmul_nc(float a, float b) {
    float c = a * b;
    asm volatile("" : "+v"(c));
    return c;
}

__device__ __forceinline__ double wave_sum_d(double v) {
#pragma unroll
    for (int o = 32; o >= 1; o >>= 1) v += __shfl_down(v, o, 64);
    return v;
}

// async global->LDS DMA, 16B per lane; lds base must be wave-uniform.
__device__ __forceinline__ void glds16(const void* g, void* l) {
    __builtin_amdgcn_global_load_lds((const __attribute__((address_space(1))) void*)g,
                                     (__attribute__((address_space(3))) void*)l, 16, 0, 0);
}

// round-to-nearest-even fp32 -> bf16 bits
__device__ __forceinline__ unsigned short f2bf(float f) {
    unsigned u = __float_as_uint(f);
    u += 0x7FFFu + ((u >> 16) & 1u);
    return (unsigned short)(u >> 16);
}

// Fused emb pass: C32[k] = fp32(||e_k||^2) (validated double wave-sum) and
// bf16-hi split store. One block per code row.
__global__ __launch_bounds__(256)
void emb_prep_kernel(const float* __restrict__ emb, float* __restrict__ c32,
                     unsigned short* __restrict__ ehi) {
    const int k = blockIdx.x;
    const float e = emb[(size_t)k * D_DIM + threadIdx.x];
    ehi[(size_t)k * D_DIM + threadIdx.x] = f2bf(e);
    const double v = (double)e;
    double s = wave_sum_d(v * v);
    __shared__ double wsm[4];
    const int lane = threadIdx.x & 63, w = threadIdx.x >> 6;
    if (lane == 0) wsm[w] = s;
    __syncthreads();
    if (threadIdx.x == 0) c32[k] = (float)(wsm[0] + wsm[1] + wsm[2] + wsm[3]);
}

// MFMA candidate filter v7: each wave owns 64 tokens (two register z-sets),
// so every e-tile ds_read_b128 feeds TWO mfmas -> LDS bytes per unit work
// halve vs v6 (which was LDS-BW-bound). Block = 256 tokens, k-split x2
// (blockIdx.y: 2048 codes, 64 tiles of 32). e-hi LDS dbuf 32 KB, both-sides
// XOR swizzle (slot s of row r holds chunk s^(r&7)). Scores biased by B0 via
// acc init -> positive -> float bits monotone as u32 -> pack code id in low
// 12 bits -> top-4 per lane-half is a pure v_max/min_u32 chain. Exact argmin
// recovered by rescoring keys within WINDOW with the validated fp32 chain.
__global__ __launch_bounds__(256)
void argmin_mfma_kernel(const float* __restrict__ z,
                        const unsigned short* __restrict__ ehi,
                        unsigned int* __restrict__ keyout)
{
    __shared__ short lds_e[2][32 * 256];   // 2 x 16 KiB

    const int tid = threadIdx.x;
    const int wv  = tid >> 6;
    const int l   = tid & 63;
    const int lr  = l & 31;          // A-row (code) / D-col (token) lane index
    const int h   = l >> 5;          // k-half within the mfma fragment
    const int tokA = blockIdx.x * 256 + wv * 64 + lr;
    const int tokB = tokA + 32;
    const int kbase = blockIdx.y * 2048;

    // z fragments for both token sets, bf16 hi only
    bf16x8 zA[16], zB[16];
#pragma unroll
    for (int st = 0; st < 16; st++) {
        {
            const float* zp = z + (size_t)tokA * D_DIM + st * 16 + h * 8;
            const float4 f0 = *(const float4*)zp;
            const float4 f1 = *(const float4*)(zp + 4);
            const float f[8] = {f0.x, f0.y, f0.z, f0.w, f1.x, f1.y, f1.z, f1.w};
#pragma unroll
            for (int j = 0; j < 8; j++) zA[st][j] = (short)f2bf(f[j]);
        }
        {
            const float* zp = z + (size_t)tokB * D_DIM + st * 16 + h * 8;
            const float4 f0 = *(const float4*)zp;
            const float4 f1 = *(const float4*)(zp + 4);
            const float f[8] = {f0.x, f0.y, f0.z, f0.w, f1.x, f1.y, f1.z, f1.w};
#pragma unroll
            for (int j = 0; j < 8; j++) zB[st][j] = (short)f2bf(f[j]);
        }
    }

    unsigned a1 = 0u, a2 = 0u, a3 = 0u, a4 = 0u;   // set-A top-4 keys
    unsigned c1 = 0u, c2 = 0u, c3 = 0u, c4 = 0u;   // set-B top-4 keys

    // stage tile ct: 16 glds16 (4/wave), 2 rows per request; source chunk
    // pre-swizzled g = lr^(r&7) so linear LDS dest + swizzled read match.
    // r&7 = 2q|h  (since (wv*4+q)&3 == q).
    auto stage = [&](int buf, int ct) {
#pragma unroll
        for (int q = 0; q < 4; q++) {
            const int rp = wv * 4 + q;
            const int r  = 2 * rp + h;
            const int g  = lr ^ ((2 * q) | h);
            const unsigned short* src =
                ehi + (size_t)(kbase + ct * 32 + r) * D_DIM + g * 8;
            glds16(src, &lds_e[buf][rp * 512]);
        }
    };

    stage(0, 0);
    __syncthreads();

    const int lk = lr & 7;
    const short* lrow0 = &lds_e[0][lr * 256];
    const short* lrow1 = &lds_e[1][lr * 256];
    const unsigned vh4 = (unsigned)(4 * h);

    int buf = 0;
    for (int ct = 0; ct < 64; ct++) {
        if (ct + 1 < 64) stage(buf ^ 1, ct + 1);

        f32x16 pA, pB;
#pragma unroll
        for (int i = 0; i < 16; i++) { pA[i] = B0; pB[i] = B0; }   // bias free

        const short* lrow = buf ? lrow1 : lrow0;
#pragma unroll
        for (int st = 0; st < 16; st++) {
            const bf16x8 eh = *(const bf16x8*)(lrow + (((2 * st + h) ^ lk) << 3));
            pA = __builtin_amdgcn_mfma_f32_32x32x16_bf16(eh, zA[st], pA, 0, 0, 0);
            pB = __builtin_amdgcn_mfma_f32_32x32x16_bf16(eh, zB[st], pB, 0, 0, 0);
        }

        // epilogue: pack biased score + code id, keep top-4 (max/min chain)
        const unsigned korb = (unsigned)(kbase + ct * 32) | vh4;
#pragma unroll
        for (int r = 0; r < 16; r++) {
            const unsigned rid = korb | (unsigned)((r & 3) + 8 * (r >> 2));
            unsigned t = (__float_as_uint(pA[r]) & 0xFFFFF000u) | rid;
            {
                const unsigned n1 = a1 > t ? a1 : t; t = a1 > t ? t : a1; a1 = n1;
                const unsigned n2 = a2 > t ? a2 : t; t = a2 > t ? t : a2; a2 = n2;
                const unsigned n3 = a3 > t ? a3 : t; t = a3 > t ? t : a3; a3 = n3;
                a4 = a4 > t ? a4 : t;
            }
            unsigned u = (__float_as_uint(pB[r]) & 0xFFFFF000u) | rid;
            {
                const unsigned n1 = c1 > u ? c1 : u; u = c1 > u ? u : c1; c1 = n1;
                const unsigned n2 = c2 > u ? c2 : u; u = c2 > u ? u : c2; c2 = n2;
                const unsigned n3 = c3 > u ? c3 : u; u = c3 > u ? u : c3; c3 = n3;
                c4 = c4 > u ? c4 : u;
            }
        }
        __syncthreads();   // readers of buf done; DMA into buf^1 drained
        buf ^= 1;
    }

    // coalesced: per token 8 dwords (h=0 then h=1), k-splits stacked by T.
    *(uint4*)(keyout + (((size_t)blockIdx.y * T_TOKENS + tokA) << 3) + vh4) =
        make_uint4(a1, a2, a3, a4);
    *(uint4*)(keyout + (((size_t)blockIdx.y * T_TOKENS + tokB) << 3) + vh4) =
        make_uint4(c1, c2, c3, c4);
}

// Rescore v7: a32 computed in-place from the staged z-tile (validated
// round-4 pairwise chain, bit-identical), 4-way parallel key rescoring
// (4 threads/token, one key-quad each), tie-rule combine, gather, fp64 loss.
__global__ __launch_bounds__(256)
void rescore_gather_kernel(const float* __restrict__ z, const float* __restrict__ emb,
                           const float* __restrict__ c32,
                           const unsigned int* __restrict__ keyout,
                           float* __restrict__ out, double* __restrict__ partials)
{
    __shared__ float zt[64][257];
    __shared__ float a32sm[64];
    __shared__ unsigned lmax[4][64];
    __shared__ float bvq[4][64];
    __shared__ int bkq[4][64];
    __shared__ int win[64];
    __shared__ double lsm[4];
    const int tid = threadIdx.x;
    const int base = blockIdx.x * 64;

    for (int idx = tid; idx < 64 * 256; idx += 256) {
        const int r = idx >> 8, c = idx & 255;
        zt[r][c] = z[(size_t)(base + r) * D_DIM + c];
    }
    __syncthreads();

    // A32[t]: np.float32 pairwise sum of z[t]**2 (validated round-4 chain)
    if (tid < 64) {
        const float* row = zt[tid];
        float S[2];
        for (int hh = 0; hh < 2; hh++) {
            const float* p = row + hh * 128;
            float r[8];
#pragma unroll
            for (int j = 0; j < 8; j++) r[j] = fmul_nc(p[j], p[j]);
            for (int m = 1; m < 16; m++) {
#pragma unroll
                for (int j = 0; j < 8; j++) r[j] += fmul_nc(p[8 * m + j], p[8 * m + j]);
            }
            S[hh] = ((r[0] + r[1]) + (r[2] + r[3])) + ((r[4] + r[5]) + (r[6] + r[7]));
        }
        a32sm[tid] = S[0] + S[1];
    }

    // per-quarter keys: qq>>1 = k-split, (qq&1)*4 = h-half
    const int ti = tid & 63, qq = tid >> 6;
    const int t = base + ti;
    const uint4 kk = *(const uint4*)(keyout +
        (((size_t)(qq >> 1) * T_TOKENS + t) << 3) + (qq & 1) * 4);
    unsigned lm = kk.x > kk.y ? kk.x : kk.y;
    lm = lm > kk.z ? lm : kk.z;
    lm = lm > kk.w ? lm : kk.w;
    lmax[qq][ti] = lm;
    __syncthreads();

    unsigned gm = lmax[0][ti];
#pragma unroll
    for (int e = 1; e < 4; e++) gm = gm > lmax[e][ti] ? gm : lmax[e][ti];
    const float thr = __uint_as_float(gm) - WINDOW;
    const float ar = a32sm[ti];
    float bestv = FLT_MAX; int bestk = INT_MAX;
    const unsigned ks[4] = {kk.x, kk.y, kk.z, kk.w};
#pragma unroll
    for (int s = 0; s < 4; s++) {
        if (__uint_as_float(ks[s]) >= thr) {
            const int k = (int)(ks[s] & 0xFFFu);
            const float* er = emb + (size_t)k * D_DIM;
            float m = 0.0f;
#pragma unroll 8
            for (int d4 = 0; d4 < 64; d4++) {
                const float4 e4 = *(const float4*)(er + 4 * d4);
                m = fmaf(zt[ti][4 * d4 + 0], e4.x, m);
                m = fmaf(zt[ti][4 * d4 + 1], e4.y, m);
                m = fmaf(zt[ti][4 * d4 + 2], e4.z, m);
                m = fmaf(zt[ti][4 * d4 + 3], e4.w, m);
            }
            const float v1 = ar - 2.0f * m;
            const float v2 = v1 + c32[k];
            if (v2 < bestv || (v2 == bestv && k < bestk)) { bestv = v2; bestk = k; }
        }
    }
    bvq[qq][ti] = bestv; bkq[qq][ti] = bestk;
    __syncthreads();

    if (tid < 64) {
        float B = bvq[0][tid];
        int I = bkq[0][tid];
#pragma unroll
        for (int e = 1; e < 4; e++) {
            const float cv = bvq[e][tid];
            const int ck = bkq[e][tid];
            if (cv < B || (cv == B && ck < I)) { B = cv; I = ck; }
        }
        win[tid] = I;
    }
    __syncthreads();

    double lacc = 0.0;
    for (int ti2 = 0; ti2 < 64; ti2++) {
        const int sel = win[ti2];
        const float ev = emb[(size_t)sel * D_DIM + tid];
        const float zv = zt[ti2][tid];
        out[(size_t)(base + ti2) * D_DIM + tid] = ev;
        if (tid == 0) out[QOFF + base + ti2] = (float)sel;
        const double df = (double)zv - (double)ev;
        lacc += df * df;
    }
    lacc = wave_sum_d(lacc);
    const int lane = tid & 63, w = tid >> 6;
    if (lane == 0) lsm[w] = lacc;
    __syncthreads();
    if (tid == 0) partials[blockIdx.x] = lsm[0] + lsm[1] + lsm[2] + lsm[3];
}

__global__ void finalize_kernel(const double* __restrict__ partials, float* __restrict__ out) {
    __shared__ double rsm[4];
    const int tid = threadIdx.x;
    double s = 0.0;
    for (int i = tid; i < 1024; i += 256) s += partials[i];
    s = wave_sum_d(s);
    if ((tid & 63) == 0) rsm[tid >> 6] = s;
    __syncthreads();
    if (tid == 0) {
        const double mean = (rsm[0] + rsm[1] + rsm[2] + rsm[3]) / (double)QOFF;
        out[QOFF + T_TOKENS] = (float)(1.25 * mean);
    }
}

extern "C" void kernel_launch(void* const* d_in, const int* in_sizes, int n_in,
                              void* d_out, int out_size, void* d_ws, size_t ws_size,
                              hipStream_t stream)
{
    const float* z = (const float*)d_in[0];
    const float* emb = (const float*)d_in[1];
    float* out = (float*)d_out;
    char* ws = (char*)d_ws;

    float* c32 = (float*)ws;                                  // 16384 B
    unsigned int* keyout = (unsigned int*)(ws + 16384);       // 2*65536*8*4 = 4194304 B
    unsigned short* ehi = (unsigned short*)(ws + 4210688);    // 2097152 B
    double* partials = (double*)(ws + 6307840);               // 8192 B

    emb_prep_kernel<<<K_EMB, 256, 0, stream>>>(emb, c32, ehi);
    argmin_mfma_kernel<<<dim3(T_TOKENS / 256, 2), 256, 0, stream>>>(z, ehi, keyout);
    rescore_gather_kernel<<<T_TOKENS / 64, 256, 0, stream>>>(z, emb, c32, keyout, out, partials);
    finalize_kernel<<<1, 256, 0, stream>>>(partials, out);
}